// Round 4
// baseline (150.897 us; speedup 1.0000x reference)
//
#include <hip/hip_runtime.h>

#define DEV __device__ __forceinline__

typedef __bf16 bf16x8 __attribute__((ext_vector_type(8)));
typedef float f32x4 __attribute__((ext_vector_type(4)));
typedef float f32x16 __attribute__((ext_vector_type(16)));
typedef unsigned u32x4 __attribute__((ext_vector_type(4)));

constexpr int S_LEN = 2048;
constexpr int DMODEL = 1024;
constexpr int NHEAD = 16;
constexpr int HDIM = 64;
constexpr int BATCH = 2;
constexpr int MROWS = BATCH * S_LEN;  // 4096
constexpr float QSCALE = 0.125f * 1.44269504088896f;  // 1/sqrt(64) * log2(e)

DEV short f2bf(float x) {
  unsigned u = __builtin_bit_cast(unsigned, x);
  unsigned r = u + 0x7fffu + ((u >> 16) & 1u);
  return (short)(r >> 16);
}

#define MFMA16(a, b, c) __builtin_amdgcn_mfma_f32_16x16x32_bf16((a), (b), (c), 0, 0, 0)
#define MFMA32(a, b, c) __builtin_amdgcn_mfma_f32_32x32x16_bf16((a), (b), (c), 0, 0, 0)
#define GLL16(g, l)                                                                     \
  __builtin_amdgcn_global_load_lds((const __attribute__((address_space(1))) void*)(g),  \
                                   (__attribute__((address_space(3))) void*)(l), 16, 0, 0)

DEV unsigned cvt_pk_bf16(float a, float b) {
  unsigned r;
  asm("v_cvt_pk_bf16_f32 %0, %1, %2" : "=v"(r) : "v"(a), "v"(b));
  return r;
}
DEV void swap32(unsigned& a, unsigned& b) {
  asm("v_permlane32_swap_b32 %0, %1" : "+v"(a), "+v"(b));
}

// ---------------- fp32 -> bf16 converts ----------------
__global__ void cvt_kernel(const float* __restrict__ in, short* __restrict__ out, int n) {
  int i = (blockIdx.x * blockDim.x + threadIdx.x) * 4;
  const int stride = gridDim.x * blockDim.x * 4;
  for (; i < n; i += stride) {
    float4 v = *(const float4*)&in[i];
    short4 r;
    r.x = f2bf(v.x);
    r.y = f2bf(v.y);
    r.z = f2bf(v.z);
    r.w = f2bf(v.w);
    *(short4*)&out[i] = r;
  }
}

__global__ void cvt_w4(const float* __restrict__ Wq, const float* __restrict__ Wk,
                       const float* __restrict__ Wv, const float* __restrict__ Wo,
                       short* __restrict__ out) {
  const float* src = blockIdx.y == 0 ? Wq : blockIdx.y == 1 ? Wk : blockIdx.y == 2 ? Wv : Wo;
  short* dst = out + (size_t)blockIdx.y * (DMODEL * DMODEL);
  int i = (blockIdx.x * blockDim.x + threadIdx.x) * 4;
  const int stride = gridDim.x * blockDim.x * 4;
  for (; i < DMODEL * DMODEL; i += stride) {
    float4 v = *(const float4*)&src[i];
    short4 r;
    r.x = f2bf(v.x);
    r.y = f2bf(v.y);
    r.z = f2bf(v.z);
    r.w = f2bf(v.w);
    *(short4*)&dst[i] = r;
  }
}

// ---------------- bf16 GEMM: C[m,e] = sum_k A[m,k] * Bt[e,k] ----------------
// mode 3: out epilogue (fp32 [M,N] + bias)
// mode 4: fused QKV epilogue (Bt is [Wq;Wk;Wv] 3072x1024; outb = Q base, K/V follow)
__global__ __launch_bounds__(256) void gemm_bt(const short* __restrict__ A,
                                               const short* __restrict__ Bt,
                                               short* __restrict__ outb,
                                               float* __restrict__ outf,
                                               const float* __restrict__ bias,
                                               const int mode) {
  constexpr int K = DMODEL;
  constexpr int N = DMODEL;
  constexpr size_t XN = (size_t)MROWS * DMODEL;
  __shared__ short As[128 * 32];
  __shared__ short Bs[128 * 32];
  const int tid = threadIdx.x;
  const int w = tid >> 6, l = tid & 63;
  const int lr = l & 15, lh = l >> 4;
  const int wr = w >> 1, wc = w & 1;
  const int tm = blockIdx.x, tn = blockIdx.y;

  f32x4 acc[4][4] = {};

  for (int kt = 0; kt < K / 32; ++kt) {
#pragma unroll
    for (int r = 0; r < 2; ++r) {
      const int c = r * 256 + tid;
      const int row = c >> 2;
      const int kc = (c & 3) * 8;
      GLL16(A + (size_t)(tm * 128 + row) * K + kt * 32 + kc, &As[(r * 256 + w * 64) * 8]);
      GLL16(Bt + (size_t)(tn * 128 + row) * K + kt * 32 + kc, &Bs[(r * 256 + w * 64) * 8]);
    }
    __syncthreads();
    bf16x8 af[4], bfr[4];
#pragma unroll
    for (int mi = 0; mi < 4; ++mi)
      af[mi] = *(const bf16x8*)&As[(wr * 64 + mi * 16 + lr) * 32 + lh * 8];
#pragma unroll
    for (int ni = 0; ni < 4; ++ni)
      bfr[ni] = *(const bf16x8*)&Bs[(wc * 64 + ni * 16 + lr) * 32 + lh * 8];
#pragma unroll
    for (int mi = 0; mi < 4; ++mi)
#pragma unroll
      for (int ni = 0; ni < 4; ++ni)
        acc[mi][ni] = MFMA16(af[mi], bfr[ni], acc[mi][ni]);
    __syncthreads();
  }

  // C/D frag layout: row = (l>>4)*4 + i, col = l&15
  const int m0 = tm * 128 + wr * 64;
  const int n0 = tn * 128 + wc * 64;
  if (mode == 3) {
#pragma unroll
    for (int mi = 0; mi < 4; ++mi)
#pragma unroll
      for (int ni = 0; ni < 4; ++ni)
#pragma unroll
        for (int i = 0; i < 4; ++i) {
          const int m = m0 + mi * 16 + lh * 4 + i;
          const int e = n0 + ni * 16 + lr;
          outf[(size_t)m * N + e] = acc[mi][ni][i] + bias[e];
        }
  } else {  // fused QKV
    const int sel = tn >> 3;
#pragma unroll
    for (int mi = 0; mi < 4; ++mi)
#pragma unroll
      for (int ni = 0; ni < 4; ++ni)
#pragma unroll
        for (int i = 0; i < 4; ++i) {
          const int m = m0 + mi * 16 + lh * 4 + i;
          const int e = n0 + ni * 16 + lr;
          const int ecol = e & (DMODEL - 1);
          const int b = m >> 11, n = m & (S_LEN - 1);
          const int h = ecol >> 6, d = ecol & (HDIM - 1);
          if (sel == 0)
            outb[((size_t)((b * NHEAD + h) * S_LEN + n)) * HDIM + d] =
                f2bf(acc[mi][ni][i] * QSCALE);
          else if (sel == 1)
            (outb + XN)[((size_t)((b * NHEAD + h) * S_LEN + n)) * HDIM + d] =
                f2bf(acc[mi][ni][i]);
          else
            (outb + 2 * XN)[((size_t)((b * NHEAD + h) * HDIM + d)) * S_LEN + n] =
                f2bf(acc[mi][ni][i]);
        }
  }
}

// swizzled LDS fragment read: 16B at slot (0..7) of a 128B row, slot ^= row&7
DEV bf16x8 ldsfrag(const short* base, int row, int slot) {
  return *(const bf16x8*)&base[row * 64 + 8 * (slot ^ (row & 7))];
}

// ---------------- flash attention, swapped-QK^T 32x32, LDS-staged KV ----------------
// grid: (S/64, B*H) = 1024 blocks, 2 waves/block; wave owns 32 q rows; KV tile = 64.
// Both waves share tmax = qb0/64 (no skip divergence). Q pre-scaled by log2(e)/8.
// K layout [B,H,S,HD]; V layout [B,H,HD,S] (= V^T rows).
__global__ __launch_bounds__(128) void attn_kernel(const short* __restrict__ Qg,
                                                   const short* __restrict__ Kg,
                                                   const short* __restrict__ Vg,
                                                   short* __restrict__ ctx) {
  __shared__ alignas(16) short Ks[2][64 * 64];
  __shared__ alignas(16) short Vs[2][64 * 64];
  const int tid = threadIdx.x;
  const int w = tid >> 6;  // 0..1
  const int l = tid & 63;
  const int lq = l & 31;
  const int h5 = l >> 5;
  const int bh = blockIdx.y;
  const int qb0 = (gridDim.x - 1 - blockIdx.x) * 64;  // big blocks first
  const int qbase = qb0 + w * 32;
  const short* Qh = Qg + (size_t)bh * (S_LEN * HDIM);
  const short* Kh = Kg + (size_t)bh * (S_LEN * HDIM);
  const short* Vh = Vg + (size_t)bh * (HDIM * S_LEN);

  // staging: each wave covers 4 stripes (stripe = 8 rows x 128B = 1KB)
  const int scol = l & 7;

  // Q as B-operand: lane holds Q[qbase+lq][c*16 + h5*8 + j]
  bf16x8 qf[4];
#pragma unroll
  for (int c = 0; c < 4; ++c)
    qf[c] = *(const bf16x8*)&Qh[(size_t)(qbase + lq) * HDIM + c * 16 + h5 * 8];

  f32x16 o0 = {}, o1 = {};
  float m = -__builtin_inff(), ll = 0.f;

  const int tmax = qb0 >> 6;

#define STAGE(T, BUF)                                                          \
  {                                                                            \
    _Pragma("unroll") for (int i = 0; i < 4; ++i) {                            \
      const int st_ = w * 4 + i;                                               \
      const int r = st_ * 8 + (l >> 3);                                        \
      const int sw = 8 * (scol ^ (l >> 3));                                    \
      GLL16(Kh + (size_t)((T)*64 + r) * HDIM + sw, &Ks[BUF][st_ * 512]);       \
      GLL16(Vh + (size_t)r * S_LEN + (T)*64 + sw, &Vs[BUF][st_ * 512]);        \
    }                                                                          \
  }

  STAGE(0, 0);
  asm volatile("s_waitcnt vmcnt(0)" ::: "memory");
  __syncthreads();

  for (int t = 0; t <= tmax; ++t) {
    const int buf = t & 1;
    if (t < tmax) STAGE(t + 1, buf ^ 1);

    const short* Ksb = Ks[buf];
    const short* Vsb = Vs[buf];
    // wave 0's upper kv sub-tile is fully masked on the diagonal: skip it
    const bool skip1 = (t == tmax) && (w == 0);

    // ---- QK^T ----
    bf16x8 kf[4];
#pragma unroll
    for (int c = 0; c < 4; ++c) kf[c] = ldsfrag(Ksb, lq, c * 2 + h5);
    f32x16 st0 = {};
#pragma unroll
    for (int c = 0; c < 4; ++c) st0 = MFMA32(kf[c], qf[c], st0);
    f32x16 st1 = {};
    if (!skip1) {
#pragma unroll
      for (int c = 0; c < 4; ++c) kf[c] = ldsfrag(Ksb, 32 + lq, c * 2 + h5);
#pragma unroll
      for (int c = 0; c < 4; ++c) st1 = MFMA32(kf[c], qf[c], st1);
    }

    if (t == tmax) {  // mask the wave's own diagonal sub-tile: crow > lq
#pragma unroll
      for (int r = 0; r < 16; ++r) {
        const int crow = (r & 3) + 8 * (r >> 2) + 4 * h5;
        if (w == 0) {
          if (crow > lq) st0[r] = -__builtin_inff();
        } else {
          if (crow > lq) st1[r] = -__builtin_inff();
        }
      }
    }

    // ---- online softmax (per q-column = lane) ----
    float pm = st0[0];
#pragma unroll
    for (int r = 1; r < 16; ++r) pm = fmaxf(pm, st0[r]);
    if (!skip1) {
#pragma unroll
      for (int r = 0; r < 16; ++r) pm = fmaxf(pm, st1[r]);
    }
    pm = fmaxf(pm, __shfl_xor(pm, 32));
    if (__any(pm - m > 8.f)) {  // defer-max
      const float nm = fmaxf(m, pm);
      const float f = __builtin_amdgcn_exp2f(m - nm);
      m = nm;
      ll *= f;
#pragma unroll
      for (int r = 0; r < 16; ++r) {
        const int srcb = ((r & 3) + 8 * (r >> 2) + 4 * h5) << 2;
        const float fr = __builtin_bit_cast(
            float, __builtin_amdgcn_ds_bpermute(srcb, __builtin_bit_cast(int, f)));
        o0[r] *= fr;
        o1[r] *= fr;
      }
    }
    float ps = 0.f;
#pragma unroll
    for (int r = 0; r < 16; ++r) {
      st0[r] = __builtin_amdgcn_exp2f(st0[r] - m);
      ps += st0[r];
    }
    if (!skip1) {
#pragma unroll
      for (int r = 0; r < 16; ++r) {
        st1[r] = __builtin_amdgcn_exp2f(st1[r] - m);
        ps += st1[r];
      }
    }
    ps += __shfl_xor(ps, 32);
    ll += ps;

    // ---- pack P -> A-operand frags (cvt_pk + permlane32_swap) + PV ----
    {
      unsigned a0 = cvt_pk_bf16(st0[0], st0[1]), b0 = cvt_pk_bf16(st0[4], st0[5]);
      unsigned a1 = cvt_pk_bf16(st0[2], st0[3]), b1 = cvt_pk_bf16(st0[6], st0[7]);
      unsigned a2 = cvt_pk_bf16(st0[8], st0[9]), b2 = cvt_pk_bf16(st0[12], st0[13]);
      unsigned a3 = cvt_pk_bf16(st0[10], st0[11]), b3 = cvt_pk_bf16(st0[14], st0[15]);
      swap32(a0, b0);
      swap32(a1, b1);
      swap32(a2, b2);
      swap32(a3, b3);
      const u32x4 pw0 = {a0, a1, b0, b1};
      const u32x4 pw1 = {a2, a3, b2, b3};
      const bf16x8 pa0 = __builtin_bit_cast(bf16x8, pw0);
      const bf16x8 pa1 = __builtin_bit_cast(bf16x8, pw1);
      o0 = MFMA32(pa0, ldsfrag(Vsb, lq, h5), o0);
      o1 = MFMA32(pa0, ldsfrag(Vsb, 32 + lq, h5), o1);
      o0 = MFMA32(pa1, ldsfrag(Vsb, lq, 2 + h5), o0);
      o1 = MFMA32(pa1, ldsfrag(Vsb, 32 + lq, 2 + h5), o1);
    }
    if (!skip1) {
      unsigned c0 = cvt_pk_bf16(st1[0], st1[1]), d0 = cvt_pk_bf16(st1[4], st1[5]);
      unsigned c1 = cvt_pk_bf16(st1[2], st1[3]), d1 = cvt_pk_bf16(st1[6], st1[7]);
      unsigned c2 = cvt_pk_bf16(st1[8], st1[9]), d2 = cvt_pk_bf16(st1[12], st1[13]);
      unsigned c3 = cvt_pk_bf16(st1[10], st1[11]), d3 = cvt_pk_bf16(st1[14], st1[15]);
      swap32(c0, d0);
      swap32(c1, d1);
      swap32(c2, d2);
      swap32(c3, d3);
      const u32x4 pw2 = {c0, c1, d0, d1};
      const u32x4 pw3 = {c2, c3, d2, d3};
      const bf16x8 pa2 = __builtin_bit_cast(bf16x8, pw2);
      const bf16x8 pa3 = __builtin_bit_cast(bf16x8, pw3);
      o0 = MFMA32(pa2, ldsfrag(Vsb, lq, 4 + h5), o0);
      o1 = MFMA32(pa2, ldsfrag(Vsb, 32 + lq, 4 + h5), o1);
      o0 = MFMA32(pa3, ldsfrag(Vsb, lq, 6 + h5), o0);
      o1 = MFMA32(pa3, ldsfrag(Vsb, 32 + lq, 6 + h5), o1);
    }

    asm volatile("s_waitcnt vmcnt(0)" ::: "memory");
    __syncthreads();
  }
#undef STAGE

  const int b = bh >> 4, h = bh & (NHEAD - 1);
#pragma unroll
  for (int r = 0; r < 16; ++r) {
    const int crow = (r & 3) + 8 * (r >> 2) + 4 * h5;
    const float lr_ = __builtin_bit_cast(
        float, __builtin_amdgcn_ds_bpermute(crow << 2, __builtin_bit_cast(int, ll)));
    const float inv = __builtin_amdgcn_rcpf(lr_);
    const size_t base = (size_t)(b * S_LEN + qbase + crow) * DMODEL + h * HDIM + lq;
    ctx[base] = f2bf(o0[r] * inv);
    ctx[base + 32] = f2bf(o1[r] * inv);
  }
}

extern "C" void kernel_launch(void* const* d_in, const int* in_sizes, int n_in,
                              void* d_out, int out_size, void* d_ws, size_t ws_size,
                              hipStream_t stream) {
  const float* x = (const float*)d_in[0];
  const float* Wq = (const float*)d_in[1];
  const float* Wk = (const float*)d_in[2];
  const float* Wv = (const float*)d_in[3];
  const float* Wo = (const float*)d_in[4];
  const float* bo = (const float*)d_in[5];

  const size_t XN = (size_t)MROWS * DMODEL;   // 4096*1024
  const size_t WN = (size_t)DMODEL * DMODEL;  // 1024*1024

  short* ws = (short*)d_ws;
  short* xb = ws;
  short* Wqb = xb + XN;  // Wq,Wk,Wv,Wo contiguous ([3072+1024][1024])
  short* Wob = Wqb + 3 * WN;
  short* Qb = Wob + WN;  // Q,K,V contiguous
  short* Kb = Qb + XN;
  short* Vb = Kb + XN;
  short* ctxb = Vb + XN;
  if (ws_size < (5 * XN + 4 * WN) * sizeof(short)) return;

  cvt_kernel<<<2048, 256, 0, stream>>>(x, xb, (int)XN);
  cvt_w4<<<dim3(256, 4), 256, 0, stream>>>(Wq, Wk, Wv, Wo, Wqb);

  gemm_bt<<<dim3(MROWS / 128, 3 * DMODEL / 128), 256, 0, stream>>>(xb, Wqb, Qb, nullptr,
                                                                   nullptr, 4);

  attn_kernel<<<dim3(S_LEN / 64, BATCH * NHEAD), 128, 0, stream>>>(Qb, Kb, Vb, ctxb);

  gemm_bt<<<dim3(MROWS / 128, DMODEL / 128), 256, 0, stream>>>(ctxb, Wob, nullptr,
                                                               (float*)d_out, bo, 3);
}

// Round 5
// 150.200 us; speedup vs baseline: 1.0046x; 1.0046x over previous
//
#include <hip/hip_runtime.h>

#define DEV __device__ __forceinline__

typedef __bf16 bf16x8 __attribute__((ext_vector_type(8)));
typedef float f32x4 __attribute__((ext_vector_type(4)));
typedef float f32x16 __attribute__((ext_vector_type(16)));
typedef unsigned u32x4 __attribute__((ext_vector_type(4)));

constexpr int S_LEN = 2048;
constexpr int DMODEL = 1024;
constexpr int NHEAD = 16;
constexpr int HDIM = 64;
constexpr int BATCH = 2;
constexpr int MROWS = BATCH * S_LEN;  // 4096
constexpr float QSCALE = 0.125f * 1.44269504088896f;  // 1/sqrt(64) * log2(e)

DEV short f2bf(float x) {
  unsigned u = __builtin_bit_cast(unsigned, x);
  unsigned r = u + 0x7fffu + ((u >> 16) & 1u);
  return (short)(r >> 16);
}

#define MFMA16(a, b, c) __builtin_amdgcn_mfma_f32_16x16x32_bf16((a), (b), (c), 0, 0, 0)
#define MFMA32(a, b, c) __builtin_amdgcn_mfma_f32_32x32x16_bf16((a), (b), (c), 0, 0, 0)
#define GLL16(g, l)                                                                     \
  __builtin_amdgcn_global_load_lds((const __attribute__((address_space(1))) void*)(g),  \
                                   (__attribute__((address_space(3))) void*)(l), 16, 0, 0)

DEV unsigned cvt_pk_bf16(float a, float b) {
  unsigned r;
  asm("v_cvt_pk_bf16_f32 %0, %1, %2" : "=v"(r) : "v"(a), "v"(b));
  return r;
}
DEV void swap32(unsigned& a, unsigned& b) {
  asm("v_permlane32_swap_b32 %0, %1" : "+v"(a), "+v"(b));
}

// ---------------- fp32 -> bf16 converts ----------------
__global__ void cvt_kernel(const float* __restrict__ in, short* __restrict__ out, int n) {
  int i = (blockIdx.x * blockDim.x + threadIdx.x) * 4;
  const int stride = gridDim.x * blockDim.x * 4;
  for (; i < n; i += stride) {
    float4 v = *(const float4*)&in[i];
    short4 r;
    r.x = f2bf(v.x);
    r.y = f2bf(v.y);
    r.z = f2bf(v.z);
    r.w = f2bf(v.w);
    *(short4*)&out[i] = r;
  }
}

__global__ void cvt_w4(const float* __restrict__ Wq, const float* __restrict__ Wk,
                       const float* __restrict__ Wv, const float* __restrict__ Wo,
                       short* __restrict__ out) {
  const float* src = blockIdx.y == 0 ? Wq : blockIdx.y == 1 ? Wk : blockIdx.y == 2 ? Wv : Wo;
  short* dst = out + (size_t)blockIdx.y * (DMODEL * DMODEL);
  int i = (blockIdx.x * blockDim.x + threadIdx.x) * 4;
  const int stride = gridDim.x * blockDim.x * 4;
  for (; i < DMODEL * DMODEL; i += stride) {
    float4 v = *(const float4*)&src[i];
    short4 r;
    r.x = f2bf(v.x);
    r.y = f2bf(v.y);
    r.z = f2bf(v.z);
    r.w = f2bf(v.w);
    *(short4*)&dst[i] = r;
  }
}

// ---------------- bf16 GEMM: C[m,e] = sum_k A[m,k] * Bt[e,k] ----------------
// mode 3: out epilogue (fp32 [M,N] + bias)
// mode 4: fused QKV epilogue (Bt is [Wq;Wk;Wv] 3072x1024; outb = Q base, K/V follow)
__global__ __launch_bounds__(256) void gemm_bt(const short* __restrict__ A,
                                               const short* __restrict__ Bt,
                                               short* __restrict__ outb,
                                               float* __restrict__ outf,
                                               const float* __restrict__ bias,
                                               const int mode) {
  constexpr int K = DMODEL;
  constexpr int N = DMODEL;
  constexpr size_t XN = (size_t)MROWS * DMODEL;
  __shared__ short As[128 * 32];
  __shared__ short Bs[128 * 32];
  const int tid = threadIdx.x;
  const int w = tid >> 6, l = tid & 63;
  const int lr = l & 15, lh = l >> 4;
  const int wr = w >> 1, wc = w & 1;
  const int tm = blockIdx.x, tn = blockIdx.y;

  f32x4 acc[4][4] = {};

  for (int kt = 0; kt < K / 32; ++kt) {
#pragma unroll
    for (int r = 0; r < 2; ++r) {
      const int c = r * 256 + tid;
      const int row = c >> 2;
      const int kc = (c & 3) * 8;
      GLL16(A + (size_t)(tm * 128 + row) * K + kt * 32 + kc, &As[(r * 256 + w * 64) * 8]);
      GLL16(Bt + (size_t)(tn * 128 + row) * K + kt * 32 + kc, &Bs[(r * 256 + w * 64) * 8]);
    }
    __syncthreads();
    bf16x8 af[4], bfr[4];
#pragma unroll
    for (int mi = 0; mi < 4; ++mi)
      af[mi] = *(const bf16x8*)&As[(wr * 64 + mi * 16 + lr) * 32 + lh * 8];
#pragma unroll
    for (int ni = 0; ni < 4; ++ni)
      bfr[ni] = *(const bf16x8*)&Bs[(wc * 64 + ni * 16 + lr) * 32 + lh * 8];
#pragma unroll
    for (int mi = 0; mi < 4; ++mi)
#pragma unroll
      for (int ni = 0; ni < 4; ++ni)
        acc[mi][ni] = MFMA16(af[mi], bfr[ni], acc[mi][ni]);
    __syncthreads();
  }

  // C/D frag layout: row = (l>>4)*4 + i, col = l&15
  const int m0 = tm * 128 + wr * 64;
  const int n0 = tn * 128 + wc * 64;
  if (mode == 3) {
#pragma unroll
    for (int mi = 0; mi < 4; ++mi)
#pragma unroll
      for (int ni = 0; ni < 4; ++ni)
#pragma unroll
        for (int i = 0; i < 4; ++i) {
          const int m = m0 + mi * 16 + lh * 4 + i;
          const int e = n0 + ni * 16 + lr;
          outf[(size_t)m * N + e] = acc[mi][ni][i] + bias[e];
        }
  } else {  // fused QKV
    const int sel = tn >> 3;
#pragma unroll
    for (int mi = 0; mi < 4; ++mi)
#pragma unroll
      for (int ni = 0; ni < 4; ++ni)
#pragma unroll
        for (int i = 0; i < 4; ++i) {
          const int m = m0 + mi * 16 + lh * 4 + i;
          const int e = n0 + ni * 16 + lr;
          const int ecol = e & (DMODEL - 1);
          const int b = m >> 11, n = m & (S_LEN - 1);
          const int h = ecol >> 6, d = ecol & (HDIM - 1);
          if (sel == 0)
            outb[((size_t)((b * NHEAD + h) * S_LEN + n)) * HDIM + d] =
                f2bf(acc[mi][ni][i] * QSCALE);
          else if (sel == 1)
            (outb + XN)[((size_t)((b * NHEAD + h) * S_LEN + n)) * HDIM + d] =
                f2bf(acc[mi][ni][i]);
          else
            (outb + 2 * XN)[((size_t)((b * NHEAD + h) * HDIM + d)) * S_LEN + n] =
                f2bf(acc[mi][ni][i]);
        }
  }
}

// ---------------- flash attention: barrier-free, wave-private KV staging ----------------
// 1 wave per block (64 thr). Wave owns 32 q rows; KV tile = 32; K,V double-buffered in
// wave-private LDS (16KB). Swapped QK^T (mfma(K,Q)) 32x32; softmax in-register.
// grid: 2048 1-D blocks; XCD-aware: xcd=bid&7 serves 4 heads (K+V 2MB fits 4MB L2).
// Q pre-scaled by log2(e)/8. K layout [B,H,S,HD]; V layout [B,H,HD,S] (= V^T rows).
// K LDS tile: [32 rows][64 shorts], 16B slot s stored at s^(row&7).
// V LDS tile: [32 rows][64 shorts], LDS row R holds V^T d-rows {2R,2R+1} (4 slots each),
//             logical slot s stored at s^(R&7).
__global__ __launch_bounds__(64) void attn_kernel(const short* __restrict__ Qg,
                                                  const short* __restrict__ Kg,
                                                  const short* __restrict__ Vg,
                                                  short* __restrict__ ctx) {
  __shared__ alignas(16) short Ks[2][32 * 64];  // 8KB
  __shared__ alignas(16) short Vs[2][32 * 64];  // 8KB
  const int l = threadIdx.x;
  const int lq = l & 31;
  const int h5 = l >> 5;
  const int bid = blockIdx.x;
  const int xcd = bid & 7;
  const int j = bid >> 3;            // 0..255 per-XCD stream index
  const int bh = xcd * 4 + (j >> 6); // 4 heads per XCD -> K/V L2-resident
  const int qi = 63 - (j & 63);      // big blocks first within each XCD stream
  const int qbase = qi * 32;
  const short* Qh = Qg + (size_t)bh * (S_LEN * HDIM);
  const short* Kh = Kg + (size_t)bh * (S_LEN * HDIM);
  const short* Vh = Vg + (size_t)bh * (HDIM * S_LEN);

  // Q as B-operand: lane holds Q[qbase+lq][c*16 + h5*8 + j]
  bf16x8 qf[4];
#pragma unroll
  for (int c = 0; c < 4; ++c)
    qf[c] = *(const bf16x8*)&Qh[(size_t)(qbase + lq) * HDIM + c * 16 + h5 * 8];

  f32x16 o0 = {}, o1 = {};
  float m = -__builtin_inff(), ll = 0.f;

  const int r8 = l >> 3;  // 0..7
  const int sc = l & 7;   // 16B slot this lane writes

#define STAGE(T, BUF)                                                           \
  {                                                                             \
    _Pragma("unroll") for (int i = 0; i < 4; ++i) {                             \
      const int R = i * 8 + r8;      /* LDS row 0..31 */                        \
      const int sg = sc ^ (R & 7);   /* logical slot this lane must fetch */    \
      GLL16(Kh + (size_t)((T)*32 + R) * HDIM + sg * 8, &Ks[BUF][i * 512]);      \
      GLL16(Vh + (size_t)(2 * R + (sg >> 2)) * S_LEN + (T)*32 + (sg & 3) * 8,   \
            &Vs[BUF][i * 512]);                                                 \
    }                                                                           \
  }

  const int tmax = qbase >> 5;  // = qi
  STAGE(0, 0);

  for (int t = 0; t <= tmax; ++t) {
    const int buf = t & 1;
    if (t < tmax) {
      STAGE(t + 1, buf ^ 1);
      asm volatile("s_waitcnt vmcnt(8)" ::: "memory");  // current buf complete
    } else {
      asm volatile("s_waitcnt vmcnt(0)" ::: "memory");
    }
    const short* Ksb = Ks[buf];
    const short* Vsb = Vs[buf];

    // ---- QK^T: S^T[kv=32][q=32], lane holds col q=lq, rows crow(r,h5) ----
    bf16x8 kf[4];
#pragma unroll
    for (int c = 0; c < 4; ++c)
      kf[c] = *(const bf16x8*)&Ksb[lq * 64 + 8 * ((c * 2 + h5) ^ (lq & 7))];
    f32x16 st = {};
    __builtin_amdgcn_s_setprio(1);
#pragma unroll
    for (int c = 0; c < 4; ++c) st = MFMA32(kf[c], qf[c], st);
    __builtin_amdgcn_s_setprio(0);

    if (t == tmax) {  // diagonal tile: mask kv-row crow > q-col lq
#pragma unroll
      for (int r = 0; r < 16; ++r) {
        const int crow = (r & 3) + 8 * (r >> 2) + 4 * h5;
        if (crow > lq) st[r] = -__builtin_inff();
      }
    }

    // ---- online softmax (per q-column = lane) ----
    float pm = st[0];
#pragma unroll
    for (int r = 1; r < 16; ++r) pm = fmaxf(pm, st[r]);
    pm = fmaxf(pm, __shfl_xor(pm, 32));
    if (__any(pm - m > 8.f)) {  // defer-max
      const float nm = fmaxf(m, pm);
      const float f = __builtin_amdgcn_exp2f(m - nm);
      m = nm;
      ll *= f;
#pragma unroll
      for (int r = 0; r < 16; ++r) {
        const int srcb = ((r & 3) + 8 * (r >> 2) + 4 * h5) << 2;
        const float fr = __builtin_bit_cast(
            float, __builtin_amdgcn_ds_bpermute(srcb, __builtin_bit_cast(int, f)));
        o0[r] *= fr;
        o1[r] *= fr;
      }
    }
    float ps = 0.f;
#pragma unroll
    for (int r = 0; r < 16; ++r) {
      st[r] = __builtin_amdgcn_exp2f(st[r] - m);
      ps += st[r];
    }
    ps += __shfl_xor(ps, 32);
    ll += ps;

    // ---- pack P -> A-operand frags (cvt_pk + permlane32_swap) ----
    unsigned a0 = cvt_pk_bf16(st[0], st[1]), b0 = cvt_pk_bf16(st[4], st[5]);
    unsigned a1 = cvt_pk_bf16(st[2], st[3]), b1 = cvt_pk_bf16(st[6], st[7]);
    unsigned a2 = cvt_pk_bf16(st[8], st[9]), b2 = cvt_pk_bf16(st[12], st[13]);
    unsigned a3 = cvt_pk_bf16(st[10], st[11]), b3 = cvt_pk_bf16(st[14], st[15]);
    swap32(a0, b0);
    swap32(a1, b1);
    swap32(a2, b2);
    swap32(a3, b3);
    const u32x4 pw0 = {a0, a1, b0, b1};
    const u32x4 pw1 = {a2, a3, b2, b3};
    const bf16x8 pa0 = __builtin_bit_cast(bf16x8, pw0);
    const bf16x8 pa1 = __builtin_bit_cast(bf16x8, pw1);

    // ---- PV: o[d][q] += sum_kv V^T[d][kv] P[kv][q] ----
    // B-operand frag for (d0, ks): lane needs V^T[d0+lq][ks*16 + h5*8 + j]:
    //   LDS row R=(d0+lq)>>1, logical slot ((d0+lq)&1)*4 + ks*2 + h5, phys ^(R&7)
    const int R0 = lq >> 1, p0 = (lq & 1) * 4 + h5;       // d0 = 0
    const int R1 = 16 + (lq >> 1);                        // d0 = 32 (same parity bits)
    const bf16x8 v00 = *(const bf16x8*)&Vsb[R0 * 64 + 8 * ((p0 + 0) ^ (R0 & 7))];
    const bf16x8 v01 = *(const bf16x8*)&Vsb[R0 * 64 + 8 * ((p0 + 2) ^ (R0 & 7))];
    const bf16x8 v10 = *(const bf16x8*)&Vsb[R1 * 64 + 8 * ((p0 + 0) ^ (R1 & 7))];
    const bf16x8 v11 = *(const bf16x8*)&Vsb[R1 * 64 + 8 * ((p0 + 2) ^ (R1 & 7))];
    __builtin_amdgcn_s_setprio(1);
    o0 = MFMA32(pa0, v00, o0);
    o1 = MFMA32(pa0, v10, o1);
    o0 = MFMA32(pa1, v01, o0);
    o1 = MFMA32(pa1, v11, o1);
    __builtin_amdgcn_s_setprio(0);
  }
#undef STAGE

  const int b = bh >> 4, h = bh & (NHEAD - 1);
#pragma unroll
  for (int r = 0; r < 16; ++r) {
    const int crow = (r & 3) + 8 * (r >> 2) + 4 * h5;
    const float lr_ = __builtin_bit_cast(
        float, __builtin_amdgcn_ds_bpermute(crow << 2, __builtin_bit_cast(int, ll)));
    const float inv = __builtin_amdgcn_rcpf(lr_);
    const size_t base = (size_t)(b * S_LEN + qbase + crow) * DMODEL + h * HDIM + lq;
    ctx[base] = f2bf(o0[r] * inv);
    ctx[base + 32] = f2bf(o1[r] * inv);
  }
}

extern "C" void kernel_launch(void* const* d_in, const int* in_sizes, int n_in,
                              void* d_out, int out_size, void* d_ws, size_t ws_size,
                              hipStream_t stream) {
  const float* x = (const float*)d_in[0];
  const float* Wq = (const float*)d_in[1];
  const float* Wk = (const float*)d_in[2];
  const float* Wv = (const float*)d_in[3];
  const float* Wo = (const float*)d_in[4];
  const float* bo = (const float*)d_in[5];

  const size_t XN = (size_t)MROWS * DMODEL;   // 4096*1024
  const size_t WN = (size_t)DMODEL * DMODEL;  // 1024*1024

  short* ws = (short*)d_ws;
  short* xb = ws;
  short* Wqb = xb + XN;  // Wq,Wk,Wv,Wo contiguous ([3072+1024][1024])
  short* Wob = Wqb + 3 * WN;
  short* Qb = Wob + WN;  // Q,K,V contiguous
  short* Kb = Qb + XN;
  short* Vb = Kb + XN;
  short* ctxb = Vb + XN;
  if (ws_size < (5 * XN + 4 * WN) * sizeof(short)) return;

  cvt_kernel<<<2048, 256, 0, stream>>>(x, xb, (int)XN);
  cvt_w4<<<dim3(256, 4), 256, 0, stream>>>(Wq, Wk, Wv, Wo, Wqb);

  gemm_bt<<<dim3(MROWS / 128, 3 * DMODEL / 128), 256, 0, stream>>>(xb, Wqb, Qb, nullptr,
                                                                   nullptr, 4);

  attn_kernel<<<2048, 64, 0, stream>>>(Qb, Kb, Vb, ctxb);

  gemm_bt<<<dim3(MROWS / 128, DMODEL / 128), 256, 0, stream>>>(ctxb, Wob, nullptr,
                                                               (float*)d_out, bo, 3);
}